// Round 1
// baseline (672.675 us; speedup 1.0000x reference)
//
#include <hip/hip_runtime.h>
#include <hip/hip_bf16.h>
#include <cstdint>
#include <cstddef>

#define S_LEN 4096
#define HIDDEN 2048
#define NHEADS 16
#define NKVH 2
#define HDIM 128

typedef __attribute__((ext_vector_type(8))) short short8;
typedef __attribute__((ext_vector_type(4))) float floatx4;

__device__ __forceinline__ short f2bf(float f) {
  uint32_t u = __builtin_bit_cast(uint32_t, f);
  uint32_t r = (u + 0x7fffu + ((u >> 16) & 1u)) >> 16;
  return (short)(uint16_t)r;
}
__device__ __forceinline__ float bf2f(short s) {
  uint32_t u = ((uint32_t)(uint16_t)s) << 16;
  return __builtin_bit_cast(float, u);
}
// XOR-swizzled offset within a row of a row-major LDS tile whose row stride
// is (mask+1)*8 shorts. Keeps 16B chunks intact; breaks power-of-2 bank strides.
__device__ __forceinline__ int swz(int row, int ks, int mask) {
  int chunk = ks >> 3;
  return ((chunk ^ (row & mask)) << 3) | (ks & 7);
}

// ---------------- cast / pack kernel ----------------
__global__ void cast_kernel(const float* __restrict__ hs, const float* __restrict__ qw,
                            const float* __restrict__ kw, const float* __restrict__ vw,
                            const float* __restrict__ qb, const float* __restrict__ kb,
                            const float* __restrict__ vb, const float* __restrict__ ow,
                            short* __restrict__ hs_b, short* __restrict__ w_b,
                            short* __restrict__ ow_b, float* __restrict__ bias) {
  const int HS_N = S_LEN * HIDDEN;
  const int QW_N = NHEADS * HDIM * HIDDEN;
  const int KW_N = NKVH * HDIM * HIDDEN;
  const int OW_N = HIDDEN * HIDDEN;
  const int TOT = HS_N + QW_N + 2 * KW_N + OW_N + 2560;
  int idx = blockIdx.x * blockDim.x + threadIdx.x;
  int stride = gridDim.x * blockDim.x;
  for (int i = idx; i < TOT; i += stride) {
    int j = i;
    if (j < HS_N) { hs_b[j] = f2bf(hs[j]); continue; }
    j -= HS_N;
    if (j < QW_N) { w_b[j] = f2bf(qw[j]); continue; }
    j -= QW_N;
    if (j < KW_N) { w_b[QW_N + j] = f2bf(kw[j]); continue; }
    j -= KW_N;
    if (j < KW_N) { w_b[QW_N + KW_N + j] = f2bf(vw[j]); continue; }
    j -= KW_N;
    if (j < OW_N) { ow_b[j] = f2bf(ow[j]); continue; }
    j -= OW_N;
    if (j < 2048) { bias[j] = qb[j]; continue; }
    j -= 2048;
    if (j < 256) { bias[2048 + j] = kb[j]; continue; }
    j -= 256;
    bias[2304 + j] = vb[j];
  }
}

// ---------------- GEMM: C[M][N] = A[M][K] @ B[N][K]^T (+bias) ----------------
// 128x128 tile, BK=64, 4 waves (2x2), each wave 64x64 via 4x4 of 16x16x32 MFMA.
template<int N_COLS, bool BIAS, bool OUT_BF16>
__global__ __launch_bounds__(256, 2) void gemm_bt(const short* __restrict__ A,
                                                  const short* __restrict__ B,
                                                  const float* __restrict__ bias,
                                                  void* __restrict__ Cout, int K) {
  __shared__ __align__(16) short As[128 * 64];
  __shared__ __align__(16) short Bs[128 * 64];
  const int tid = threadIdx.x;
  const int lane = tid & 63;
  const int w = tid >> 6;
  const int wr = w >> 1, wc = w & 1;
  const int m0 = blockIdx.y * 128;
  const int n0 = blockIdx.x * 128;
  const int l15 = lane & 15, q = lane >> 4;

  floatx4 acc[4][4];
#pragma unroll
  for (int i = 0; i < 4; i++)
#pragma unroll
    for (int j = 0; j < 4; j++) acc[i][j] = (floatx4){0.f, 0.f, 0.f, 0.f};

  for (int k0 = 0; k0 < K; k0 += 64) {
#pragma unroll
    for (int r = 0; r < 4; r++) {
      int ci = r * 256 + tid;          // 1024 chunks of 16B per tile
      int row = ci >> 3, cc = (ci & 7) << 3;
      short8 av = *(const short8*)(A + (size_t)(m0 + row) * K + k0 + cc);
      *(short8*)(&As[row * 64 + swz(row, cc, 7)]) = av;
      short8 bv = *(const short8*)(B + (size_t)(n0 + row) * K + k0 + cc);
      *(short8*)(&Bs[row * 64 + swz(row, cc, 7)]) = bv;
    }
    __syncthreads();
#pragma unroll
    for (int ko = 0; ko < 2; ko++) {
      short8 a[4], b[4];
#pragma unroll
      for (int i = 0; i < 4; i++) {
        int m = wr * 64 + i * 16 + l15;
        a[i] = *(const short8*)(&As[m * 64 + swz(m, ko * 32 + q * 8, 7)]);
      }
#pragma unroll
      for (int j = 0; j < 4; j++) {
        int n = wc * 64 + j * 16 + l15;
        b[j] = *(const short8*)(&Bs[n * 64 + swz(n, ko * 32 + q * 8, 7)]);
      }
#pragma unroll
      for (int i = 0; i < 4; i++)
#pragma unroll
        for (int j = 0; j < 4; j++)
          acc[i][j] = __builtin_amdgcn_mfma_f32_16x16x32_bf16(a[i], b[j], acc[i][j], 0, 0, 0);
    }
    __syncthreads();
  }
#pragma unroll
  for (int i = 0; i < 4; i++)
#pragma unroll
    for (int j = 0; j < 4; j++) {
      int n = n0 + wc * 64 + j * 16 + l15;
      float bv = 0.f;
      if (BIAS) bv = bias[n];
#pragma unroll
      for (int r = 0; r < 4; r++) {
        int m = m0 + wr * 64 + i * 16 + q * 4 + r;
        float v = acc[i][j][r] + bv;
        if (OUT_BF16) ((short*)Cout)[(size_t)m * N_COLS + n] = f2bf(v);
        else          ((float*)Cout)[(size_t)m * N_COLS + n] = v;
      }
    }
}

// ---------------- RoPE + scatter ----------------
// qkv [S][2560] bf16 -> Qr[16][S][128] (scaled by 1/sqrt(HD)*log2e), Kr[2][S][128], Vt[2][128][S]
__global__ void rope_kernel(const short* __restrict__ qkv, short* __restrict__ Qr,
                            short* __restrict__ Kr, short* __restrict__ Vt) {
  const int s = blockIdx.x;
  const int tid = threadIdx.x;
  const short* row = qkv + (size_t)s * 2560;
  const float QSCALE = 0.08838834764831845f * 1.4426950408889634f; // 1/sqrt(128)*log2(e)
  const float L2T_64 = 19.931568569324174f / 64.0f;                 // log2(1e6)/64
  for (int p = tid; p < 1152; p += 256) {   // 18 heads * 64 pairs (16 Q + 2 K)
    int h = p >> 6;
    int d = p & 63;
    int base = h * 128;
    float x1 = bf2f(row[base + d]);
    float x2 = bf2f(row[base + d + 64]);
    float invf = exp2f(-(float)d * L2T_64);
    float ang = (float)s * invf;
    float sn, cs;
    sincosf(ang, &sn, &cs);
    float o1 = x1 * cs - x2 * sn;
    float o2 = x2 * cs + x1 * sn;
    if (h < 16) {
      size_t o = ((size_t)h * S_LEN + s) * HDIM;
      Qr[o + d] = f2bf(o1 * QSCALE);
      Qr[o + d + 64] = f2bf(o2 * QSCALE);
    } else {
      size_t o = ((size_t)(h - 16) * S_LEN + s) * HDIM;
      Kr[o + d] = f2bf(o1);
      Kr[o + d + 64] = f2bf(o2);
    }
  }
  for (int p = tid; p < 256; p += 256) {    // V: transpose-scatter
    int kv = p >> 7, d = p & 127;
    Vt[((size_t)kv * HDIM + d) * S_LEN + s] = row[2304 + p];
  }
}

// ---------------- attention, two passes ----------------
// PASS 0: row max (base-2) + sumexp2 -> ml.  PASS 1: probs, PV, colsum atomics, O write.
template<int PASS>
__global__ __launch_bounds__(256, 2) void attn_kernel(
    const short* __restrict__ Qr, const short* __restrict__ Kr,
    const short* __restrict__ Vt, float* __restrict__ ml,
    short* __restrict__ attn_out, float* __restrict__ acc_out) {
  __shared__ __align__(16) short Ks[64 * 128];
  __shared__ __align__(16) short Vs[PASS ? 128 * 64 : 8];
  __shared__ __align__(16) short Ps[PASS ? 4 * 32 * 64 : 8];

  const int bid = blockIdx.x;
  const int h = bid & 15;
  const int qt = 31 - (bid >> 4);   // big causal tiles launch first
  const int kv = h >> 3;            // G = 8
  const int tid = threadIdx.x;
  const int lane = tid & 63;
  const int w = tid >> 6;
  const int l15 = lane & 15, q = lane >> 4;
  const int r0w = qt * 128 + w * 32;

  short8 aq[2][4];
#pragma unroll
  for (int i = 0; i < 2; i++)
#pragma unroll
    for (int ko = 0; ko < 4; ko++) {
      int m = r0w + i * 16 + l15;
      aq[i][ko] = *(const short8*)(Qr + ((size_t)h * S_LEN + m) * HDIM + ko * 32 + q * 8);
    }

  float mrun[2][4], lrun[2][4], mrow[2][4], linv[2][4];
#pragma unroll
  for (int i = 0; i < 2; i++)
#pragma unroll
    for (int r = 0; r < 4; r++) { mrun[i][r] = -1e30f; lrun[i][r] = 0.f; }
  if (PASS == 1) {
#pragma unroll
    for (int i = 0; i < 2; i++)
#pragma unroll
      for (int r = 0; r < 4; r++) {
        int m = r0w + i * 16 + q * 4 + r;
        mrow[i][r] = ml[h * S_LEN + m];
        linv[i][r] = 1.0f / ml[NHEADS * S_LEN + h * S_LEN + m];
      }
  }
  floatx4 acc_o[2][8];
  if (PASS == 1) {
#pragma unroll
    for (int i = 0; i < 2; i++)
#pragma unroll
      for (int dt = 0; dt < 8; dt++) acc_o[i][dt] = (floatx4){0.f, 0.f, 0.f, 0.f};
  }

  const int nsteps = (qt + 1) * 2;
  for (int kt = 0; kt < nsteps; kt++) {
    const int j0 = kt * 64;
    __syncthreads();
#pragma unroll
    for (int r = 0; r < 4; r++) {
      int ci = r * 256 + tid;
      int row = ci >> 4, cc = (ci & 15) << 3;      // K tile: 64 x 128
      short8 kvv = *(const short8*)(Kr + ((size_t)kv * S_LEN + j0 + row) * HDIM + cc);
      *(short8*)(&Ks[row * 128 + swz(row, cc, 15)]) = kvv;
      if (PASS == 1) {
        int vr = ci >> 3, vc = (ci & 7) << 3;      // V tile: 128(d) x 64(j)
        short8 vv = *(const short8*)(Vt + ((size_t)kv * HDIM + vr) * S_LEN + j0 + vc);
        *(short8*)(&Vs[vr * 64 + swz(vr, vc, 7)]) = vv;
      }
    }
    __syncthreads();

    if (j0 > r0w + 31) continue;   // wave fully masked this step (barriers balanced)

    floatx4 sacc[2][4];
#pragma unroll
    for (int i = 0; i < 2; i++)
#pragma unroll
      for (int jt = 0; jt < 4; jt++) sacc[i][jt] = (floatx4){0.f, 0.f, 0.f, 0.f};
#pragma unroll
    for (int ko = 0; ko < 4; ko++) {
      short8 b[4];
#pragma unroll
      for (int jt = 0; jt < 4; jt++) {
        int j = jt * 16 + l15;
        b[jt] = *(const short8*)(&Ks[j * 128 + swz(j, ko * 32 + q * 8, 15)]);
      }
#pragma unroll
      for (int i = 0; i < 2; i++)
#pragma unroll
        for (int jt = 0; jt < 4; jt++)
          sacc[i][jt] = __builtin_amdgcn_mfma_f32_16x16x32_bf16(aq[i][ko], b[jt], sacc[i][jt], 0, 0, 0);
    }

    if (j0 + 63 > r0w) {           // boundary: apply causal mask
#pragma unroll
      for (int i = 0; i < 2; i++)
#pragma unroll
        for (int jt = 0; jt < 4; jt++)
#pragma unroll
          for (int r = 0; r < 4; r++) {
            int m = r0w + i * 16 + q * 4 + r;
            int j = j0 + jt * 16 + l15;
            if (j > m) sacc[i][jt][r] = -1e30f;
          }
    }

    if (PASS == 0) {
#pragma unroll
      for (int i = 0; i < 2; i++)
#pragma unroll
        for (int r = 0; r < 4; r++) {
          float mx = fmaxf(fmaxf(sacc[i][0][r], sacc[i][1][r]),
                           fmaxf(sacc[i][2][r], sacc[i][3][r]));
#pragma unroll
          for (int off = 1; off < 16; off <<= 1) mx = fmaxf(mx, __shfl_xor(mx, off));
          float mnew = fmaxf(mrun[i][r], mx);
          float sum = 0.f;
#pragma unroll
          for (int jt = 0; jt < 4; jt++) sum += exp2f(sacc[i][jt][r] - mnew);
#pragma unroll
          for (int off = 1; off < 16; off <<= 1) sum += __shfl_xor(sum, off);
          lrun[i][r] = lrun[i][r] * exp2f(mrun[i][r] - mnew) + sum;
          mrun[i][r] = mnew;
        }
    } else {
      float colsum[4] = {0.f, 0.f, 0.f, 0.f};
      short* myP = &Ps[w * 32 * 64];   // wave-private: no barrier needed
#pragma unroll
      for (int i = 0; i < 2; i++)
#pragma unroll
        for (int jt = 0; jt < 4; jt++)
#pragma unroll
          for (int r = 0; r < 4; r++) {
            float p = exp2f(sacc[i][jt][r] - mrow[i][r]) * linv[i][r];
            colsum[jt] += p;
            int prow = i * 16 + q * 4 + r;
            int pcol = jt * 16 + l15;
            myP[prow * 64 + swz(prow, pcol, 7)] = f2bf(p);
          }
#pragma unroll
      for (int jt = 0; jt < 4; jt++) {
        float cs = colsum[jt];
        cs += __shfl_xor(cs, 16);
        cs += __shfl_xor(cs, 32);
        if (q == 0) atomicAdd(&acc_out[kv * S_LEN + j0 + jt * 16 + l15], cs * 0.125f);
      }
#pragma unroll
      for (int ko2 = 0; ko2 < 2; ko2++) {
        short8 ap[2];
#pragma unroll
        for (int i = 0; i < 2; i++) {
          int prow = i * 16 + l15;
          ap[i] = *(const short8*)(&myP[prow * 64 + swz(prow, ko2 * 32 + q * 8, 7)]);
        }
#pragma unroll
        for (int dt = 0; dt < 8; dt++) {
          int d = dt * 16 + l15;
          short8 bv = *(const short8*)(&Vs[d * 64 + swz(d, ko2 * 32 + q * 8, 7)]);
#pragma unroll
          for (int i = 0; i < 2; i++)
            acc_o[i][dt] = __builtin_amdgcn_mfma_f32_16x16x32_bf16(ap[i], bv, acc_o[i][dt], 0, 0, 0);
        }
      }
    }
  }

  if (PASS == 0) {
    if (l15 == 0) {
#pragma unroll
      for (int i = 0; i < 2; i++)
#pragma unroll
        for (int r = 0; r < 4; r++) {
          int m = r0w + i * 16 + q * 4 + r;
          ml[h * S_LEN + m] = mrun[i][r];
          ml[NHEADS * S_LEN + h * S_LEN + m] = lrun[i][r];
        }
    }
  } else {
#pragma unroll
    for (int i = 0; i < 2; i++)
#pragma unroll
      for (int dt = 0; dt < 8; dt++)
#pragma unroll
        for (int r = 0; r < 4; r++) {
          int m = r0w + i * 16 + q * 4 + r;
          attn_out[(size_t)m * HIDDEN + h * HDIM + dt * 16 + l15] = f2bf(acc_o[i][dt][r]);
        }
  }
}

// ---------------- launch ----------------
extern "C" void kernel_launch(void* const* d_in, const int* in_sizes, int n_in,
                              void* d_out, int out_size, void* d_ws, size_t ws_size,
                              hipStream_t stream) {
  const float* hs = (const float*)d_in[0];
  const float* qw = (const float*)d_in[1];
  const float* qb = (const float*)d_in[2];
  const float* kw = (const float*)d_in[3];
  const float* kb = (const float*)d_in[4];
  const float* vw = (const float*)d_in[5];
  const float* vb = (const float*)d_in[6];
  const float* ow = (const float*)d_in[7];

  char* p = (char*)d_ws;
  auto alloc = [&](size_t bytes) { char* r = p; p += (bytes + 255) & ~(size_t)255; return r; };
  short* hs_b   = (short*)alloc((size_t)S_LEN * HIDDEN * 2);
  short* w_b    = (short*)alloc((size_t)2560 * HIDDEN * 2);
  short* ow_b   = (short*)alloc((size_t)HIDDEN * HIDDEN * 2);
  float* bias   = (float*)alloc(2560 * 4);
  short* qkv_t  = (short*)alloc((size_t)S_LEN * 2560 * 2);
  short* Qr     = (short*)alloc((size_t)NHEADS * S_LEN * HDIM * 2);
  short* Kr     = (short*)alloc((size_t)NKVH * S_LEN * HDIM * 2);
  short* Vt     = (short*)alloc((size_t)NKVH * HDIM * S_LEN * 2);
  float* ml     = (float*)alloc((size_t)2 * NHEADS * S_LEN * 4);
  short* attn_b = (short*)alloc((size_t)S_LEN * HIDDEN * 2);

  float* out = (float*)d_out;
  float* acc_out = out + (size_t)S_LEN * HIDDEN;

  hipMemsetAsync(acc_out, 0, (size_t)NKVH * S_LEN * sizeof(float), stream);
  cast_kernel<<<4096, 256, 0, stream>>>(hs, qw, kw, vw, qb, kb, vb, ow, hs_b, w_b, ow_b, bias);
  gemm_bt<2560, true, true><<<dim3(20, 32), 256, 0, stream>>>(hs_b, w_b, bias, qkv_t, HIDDEN);
  rope_kernel<<<S_LEN, 256, 0, stream>>>(qkv_t, Qr, Kr, Vt);
  attn_kernel<0><<<512, 256, 0, stream>>>(Qr, Kr, Vt, ml, nullptr, nullptr);
  attn_kernel<1><<<512, 256, 0, stream>>>(Qr, Kr, Vt, ml, attn_b, acc_out);
  gemm_bt<2048, false, false><<<dim3(16, 32), 256, 0, stream>>>(attn_b, ow_b, nullptr, out, HIDDEN);
}